// Round 2
// baseline (1103.728 us; speedup 1.0000x reference)
//
#include <hip/hip_runtime.h>

#define NEGV (-1e9f)

static const int B_ = 16;
static const int T_ = 2048;
static const int S_ = 512;
static const int C_ = 192;

// ---------------- prep: As = m*s2r, Bm = s2r, nc14[b,s] = nc1+nc4 ----------------
__global__ __launch_bounds__(256)
void prep_kernel(const float* __restrict__ m_p, const float* __restrict__ logs_p,
                 float* __restrict__ As, float* __restrict__ Bm,
                 float* __restrict__ nc14) {
    int wid = (blockIdx.x * blockDim.x + threadIdx.x) >> 6;   // (b*S+s)
    int lane = threadIdx.x & 63;
    if (wid >= B_ * S_) return;
    const float HALF_LOG_2PI = 0.9189385332046727f;
    const float* mrow = m_p   + (size_t)wid * C_;
    const float* lrow = logs_p + (size_t)wid * C_;
    float* arow = As + (size_t)wid * C_;
    float* brow = Bm + (size_t)wid * C_;
    float tot = 0.f;
#pragma unroll
    for (int q = 0; q < 3; ++q) {
        int c = lane + q * 64;
        float m  = mrow[c];
        float lp = lrow[c];
        float s2r = __expf(-2.f * lp);
        arow[c] = m * s2r;
        brow[c] = s2r;
        tot += (-HALF_LOG_2PI - lp) + (-0.5f * m * m * s2r);
    }
#pragma unroll
    for (int off = 32; off > 0; off >>= 1) tot += __shfl_xor(tot, off);
    if (lane == 0) nc14[wid] = tot;
}

// ---------------- GEMM: ll[b,t,s] = masked(nc14 + sum_c z*As + (-0.5 z^2)*Bm) ----------------
#define BM 64
#define BN 64
#define KB 16
__global__ __launch_bounds__(256)
void gemm_kernel(const float* __restrict__ z_p,
                 const float* __restrict__ As, const float* __restrict__ Bm,
                 const float* __restrict__ nc14,
                 const int* __restrict__ textlen, const int* __restrict__ mellen,
                 float* __restrict__ ll) {
    __shared__ float Zs[KB][BM + 4];
    __shared__ float Asb[KB][BN + 4];
    __shared__ float Bsb[KB][BN + 4];
    const int b  = blockIdx.z;
    const int t0 = blockIdx.y * BM;
    const int s0 = blockIdx.x * BN;
    const int tid = threadIdx.x;
    const int tx = tid & 15, ty = tid >> 4;
    const int i  = tid >> 2;             // 0..63 row within tile
    const int j4 = (tid & 3) * 4;        // 0,4,8,12 col within k-slab

    float acc[4][4];
#pragma unroll
    for (int a = 0; a < 4; ++a)
#pragma unroll
        for (int bq = 0; bq < 4; ++bq) acc[a][bq] = 0.f;

    const float* zb = z_p + ((size_t)b * T_ + t0 + i) * C_ + j4;
    const float* ab = As  + ((size_t)b * S_ + s0 + i) * C_ + j4;
    const float* bb = Bm  + ((size_t)b * S_ + s0 + i) * C_ + j4;

    for (int kt = 0; kt < C_ / KB; ++kt) {
        const int c0 = kt * KB;
        float4 zv = *(const float4*)(zb + c0);
        float4 av = *(const float4*)(ab + c0);
        float4 bv = *(const float4*)(bb + c0);
        __syncthreads();
        Zs[j4 + 0][i] = zv.x; Zs[j4 + 1][i] = zv.y; Zs[j4 + 2][i] = zv.z; Zs[j4 + 3][i] = zv.w;
        Asb[j4 + 0][i] = av.x; Asb[j4 + 1][i] = av.y; Asb[j4 + 2][i] = av.z; Asb[j4 + 3][i] = av.w;
        Bsb[j4 + 0][i] = bv.x; Bsb[j4 + 1][i] = bv.y; Bsb[j4 + 2][i] = bv.z; Bsb[j4 + 3][i] = bv.w;
        __syncthreads();
#pragma unroll
        for (int c = 0; c < KB; ++c) {
            float zr[4], wr[4], a4[4], b4[4];
#pragma unroll
            for (int r = 0; r < 4; ++r) {
                zr[r] = Zs[c][ty * 4 + r];
                a4[r] = Asb[c][tx * 4 + r];
                b4[r] = Bsb[c][tx * 4 + r];
            }
#pragma unroll
            for (int r = 0; r < 4; ++r) wr[r] = -0.5f * zr[r] * zr[r];
#pragma unroll
            for (int r = 0; r < 4; ++r)
#pragma unroll
                for (int q = 0; q < 4; ++q) {
                    acc[r][q] += zr[r] * a4[q];
                    acc[r][q] += wr[r] * b4[q];
                }
        }
    }

    const int ml = mellen[b], tl = textlen[b];
    float nc[4];
#pragma unroll
    for (int q = 0; q < 4; ++q) nc[q] = nc14[b * S_ + s0 + tx * 4 + q];
#pragma unroll
    for (int r = 0; r < 4; ++r) {
        const int t = t0 + ty * 4 + r;
        const bool tm = (t < ml);
        float* orow = ll + ((size_t)b * T_ + t) * S_ + s0 + tx * 4;
#pragma unroll
        for (int q = 0; q < 4; ++q) {
            const int s = s0 + tx * 4 + q;
            orow[q] = (tm && s < tl) ? (acc[r][q] + nc[q]) : NEGV;
        }
    }
}

// ---------------- MAS forward: LDS ring + global_load_lds, counted vmcnt ----------------
#define DEPTH 24            // rows in flight (48 KB LDS ring, 48 outstanding loads)

__device__ __forceinline__ void gload_lds16(const float* g, float* l) {
    __builtin_amdgcn_global_load_lds(
        (const __attribute__((address_space(1))) void*)g,
        (__attribute__((address_space(3))) void*)l,
        16, 0, 0);
}

__global__ __launch_bounds__(64)
void mas_forward(const float* __restrict__ ll, unsigned char* __restrict__ dir) {
    __shared__ float ring[DEPTH * 512];   // 48 KB, DEPTH rows of S_ floats
    const int b = blockIdx.x;
    const int lane = threadIdx.x;
    const float* llb = ll + (size_t)b * T_ * S_;
    unsigned char* db = dir + ((size_t)b * T_) * 64 + lane;

    // prologue: fill the ring (2 x 16B DMA per 2KB row)
#pragma unroll 4
    for (int r = 0; r < DEPTH; ++r) {
        const float* grow = llb + (size_t)r * S_;
        gload_lds16(grow + lane * 4,       &ring[r * 512]);
        gload_lds16(grow + 256 + lane * 4, &ring[r * 512 + 256]);
    }

    float p[8];
#pragma unroll
    for (int j = 0; j < 8; ++j) p[j] = 0.f;
    const int sbase = lane * 8;
    int slot = 0;

    for (int t = 0; t < T_; ++t) {
        // oldest row (t) has landed when <= 2*(DEPTH-1) loads outstanding
        asm volatile("s_waitcnt vmcnt(46)" ::: "memory");
        __builtin_amdgcn_sched_barrier(0);

        const float* lrow = &ring[slot * 512 + lane * 8];
        float4 c0 = *(const float4*)(lrow);
        float4 c1 = *(const float4*)(lrow + 4);
        asm volatile("s_waitcnt lgkmcnt(0)" ::: "memory");
        __builtin_amdgcn_sched_barrier(0);

        // reissue prefetch into the slot we just consumed
        const int tn = t + DEPTH;
        if (tn < T_) {
            const float* grow = llb + (size_t)tn * S_;
            gload_lds16(grow + lane * 4,       &ring[slot * 512]);
            gload_lds16(grow + 256 + lane * 4, &ring[slot * 512 + 256]);
        }
        slot = (slot + 1 == DEPTH) ? 0 : slot + 1;

        float cur[8];
        cur[0] = c0.x; cur[1] = c0.y; cur[2] = c0.z; cur[3] = c0.w;
        cur[4] = c1.x; cur[5] = c1.y; cur[6] = c1.z; cur[7] = c1.w;

        float prevlast = __shfl_up(p[7], 1);
        if (lane == 0) prevlast = NEGV;
        float prev[8];
        prev[0] = prevlast;
#pragma unroll
        for (int j = 1; j < 8; ++j) prev[j] = p[j - 1];
        unsigned bits = 0;
#pragma unroll
        for (int j = 0; j < 8; ++j) bits |= (p[j] >= prev[j] ? 1u : 0u) << j;
#pragma unroll
        for (int j = 0; j < 8; ++j) {
            const float v = fmaxf(p[j], prev[j]) + cur[j];
            p[j] = (sbase + j <= t) ? v : NEGV;
        }
        db[(size_t)t * 64] = (unsigned char)bits;
    }
}

// ---------------- MAS backward: 8-step speculative groups, emits idx[b,t] ----------------
__global__ __launch_bounds__(64)
void mas_backward(const unsigned char* __restrict__ dir,
                  const int* __restrict__ textlen, const int* __restrict__ mellen,
                  int* __restrict__ idx_arr) {
    const int b = blockIdx.x;
    const int lane = threadIdx.x;
    const int tl = textlen[b], ml = mellen[b];
    for (int t = ml + lane; t < T_; t += 64) idx_arr[b * T_ + t] = -1;
    const unsigned char* db = dir + ((size_t)b * T_) * 64;
    int idx = tl - 1;
    int t_hi = ml - 1;
    while (t_hi >= 0) {
        const int lo = idx - 7;
        const int blo = (lo > 0 ? lo : 0) >> 3;
        const int bhi = idx >> 3;
        const int t = t_hi - lane;
        unsigned v = 0;
        if (lane < 8 && t >= 0) {
            unsigned b0 = db[(size_t)t * 64 + blo];
            unsigned b1 = db[(size_t)t * 64 + bhi];
            v = b0 | (b1 << 8);
        }
        unsigned vk[8];
#pragma unroll
        for (int k = 0; k < 8; ++k) vk[k] = __shfl((int)v, k);
        int emit = -1;
#pragma unroll
        for (int k = 0; k < 8; ++k) {
            const int tt = t_hi - k;
            if (tt < 0) break;
            if (lane == k) emit = idx;
            const int sb = idx >> 3;
            const unsigned byte = (sb == bhi) ? (vk[k] >> 8) : (vk[k] & 0xffu);
            const int stay = (byte >> (idx & 7)) & 1;
            idx -= (1 - stay);
            if (idx < 0) idx = 0;
        }
        const int tt = t_hi - lane;
        if (lane < 8 && tt >= 0) idx_arr[b * T_ + tt] = emit;
        t_hi -= 8;
    }
}

// ---------------- scatter the one-hots ----------------
__global__ __launch_bounds__(256)
void scatter_attn(const int* __restrict__ idx_arr, float* __restrict__ attn) {
    const int f = blockIdx.x * blockDim.x + threadIdx.x;  // b*T + t
    if (f >= B_ * T_) return;
    const int idx = idx_arr[f];
    if (idx >= 0) attn[(size_t)f * S_ + idx] = 1.0f;
}

// ---------------- per-frame kl ----------------
__global__ __launch_bounds__(256)
void kl_frames(const float* __restrict__ m_p, const float* __restrict__ logs_p,
               const float* __restrict__ z_p, const float* __restrict__ logs_q,
               const int* __restrict__ idx_arr, const int* __restrict__ mellen,
               float* __restrict__ frame_kl) {
    const int wid = (blockIdx.x * blockDim.x + threadIdx.x) >> 6;  // b*T + t
    const int lane = threadIdx.x & 63;
    if (wid >= B_ * T_) return;
    const int b = wid >> 11;       // T_ = 2048
    const int t = wid & (T_ - 1);
    const int ml = mellen[b];
    float total = 0.f;
    if (t < ml) {
        const int idx = idx_arr[wid];
        const float* mr = m_p    + ((size_t)b * S_ + idx) * C_;
        const float* lr = logs_p + ((size_t)b * S_ + idx) * C_;
        const float* zr = z_p    + (size_t)wid * C_;
        const float* qr = logs_q + (size_t)wid * C_;
#pragma unroll
        for (int q = 0; q < 3; ++q) {
            const int c = lane + q * 64;
            const float le = lr[c];
            const float d = zr[c] - mr[c];
            total += le - qr[c] - 0.5f + 0.5f * d * d * __expf(-2.f * le);
        }
    }
#pragma unroll
    for (int off = 32; off > 0; off >>= 1) total += __shfl_xor(total, off);
    if (lane == 0) frame_kl[wid] = total;
}

// ---------------- deterministic final reduce ----------------
__global__ __launch_bounds__(256)
void kl_reduce(const float* __restrict__ frame_kl, const int* __restrict__ mellen,
               float* __restrict__ out) {
    __shared__ float sm[256];
    const int tid = threadIdx.x;
    float s = 0.f;
    for (int k = tid; k < B_ * T_; k += 256) s += frame_kl[k];
    sm[tid] = s;
    __syncthreads();
    for (int off = 128; off > 0; off >>= 1) {
        if (tid < off) sm[tid] += sm[tid + off];
        __syncthreads();
    }
    if (tid == 0) {
        int sum_ml = 0;
        for (int bq = 0; bq < B_; ++bq) sum_ml += mellen[bq];
        out[0] = sm[0] / (float)sum_ml;
    }
}

extern "C" void kernel_launch(void* const* d_in, const int* in_sizes, int n_in,
                              void* d_out, int out_size, void* d_ws, size_t ws_size,
                              hipStream_t stream) {
    const float* m_p    = (const float*)d_in[0];
    const float* logs_p = (const float*)d_in[1];
    const float* z_p    = (const float*)d_in[2];
    const float* logs_q = (const float*)d_in[3];
    const int*   textlen = (const int*)d_in[4];
    const int*   mellen  = (const int*)d_in[5];

    float* out = (float*)d_out;
    float* attn = out + 1;                 // [B,T,S] region; also used as ll scratch
    float* ll = attn;

    char* ws = (char*)d_ws;
    const size_t OFF_AS   = 0;
    const size_t OFF_BM   = OFF_AS + (size_t)B_ * S_ * C_ * 4;   //  6291456
    const size_t OFF_NC   = OFF_BM + (size_t)B_ * S_ * C_ * 4;   // 12582912
    const size_t OFF_DIR  = OFF_NC + (size_t)B_ * S_ * 4;        // 12615680
    const size_t OFF_IDX  = OFF_DIR + (size_t)B_ * T_ * 64;      // 14712832
    const size_t OFF_FKL  = OFF_IDX + (size_t)B_ * T_ * 4;       // 14843904
    float* As   = (float*)(ws + OFF_AS);
    float* Bm   = (float*)(ws + OFF_BM);
    float* nc14 = (float*)(ws + OFF_NC);
    unsigned char* dir = (unsigned char*)(ws + OFF_DIR);
    int* idx_arr = (int*)(ws + OFF_IDX);
    float* frame_kl = (float*)(ws + OFF_FKL);

    // 1. prep
    prep_kernel<<<(B_ * S_) / 4, 256, 0, stream>>>(m_p, logs_p, As, Bm, nc14);
    // 2. score GEMM -> ll (in d_out attn region)
    gemm_kernel<<<dim3(S_ / BN, T_ / BM, B_), 256, 0, stream>>>(
        z_p, As, Bm, nc14, textlen, mellen, ll);
    // 3. MAS forward
    mas_forward<<<B_, 64, 0, stream>>>(ll, dir);
    // 4. MAS backward -> idx per frame
    mas_backward<<<B_, 64, 0, stream>>>(dir, textlen, mellen, idx_arr);
    // 5. zero attn then scatter ones
    hipMemsetAsync(attn, 0, (size_t)B_ * T_ * S_ * 4, stream);
    scatter_attn<<<(B_ * T_ + 255) / 256, 256, 0, stream>>>(idx_arr, attn);
    // 6. kl
    kl_frames<<<(B_ * T_) / 4, 256, 0, stream>>>(m_p, logs_p, z_p, logs_q,
                                                 idx_arr, mellen, frame_kl);
    kl_reduce<<<1, 256, 0, stream>>>(frame_kl, mellen, out);
}

// Round 3
// 646.601 us; speedup vs baseline: 1.7070x; 1.7070x over previous
//
#include <hip/hip_runtime.h>

#define NEGV (-1e9f)

static const int B_ = 16;
static const int T_ = 2048;
static const int S_ = 512;
static const int C_ = 192;

// ---------------- prep: As = m*s2r, Bm = s2r, nc14[b,s] = nc1+nc4 ----------------
__global__ __launch_bounds__(256)
void prep_kernel(const float* __restrict__ m_p, const float* __restrict__ logs_p,
                 float* __restrict__ As, float* __restrict__ Bm,
                 float* __restrict__ nc14) {
    int wid = (blockIdx.x * blockDim.x + threadIdx.x) >> 6;   // (b*S+s)
    int lane = threadIdx.x & 63;
    if (wid >= B_ * S_) return;
    const float HALF_LOG_2PI = 0.9189385332046727f;
    const float* mrow = m_p   + (size_t)wid * C_;
    const float* lrow = logs_p + (size_t)wid * C_;
    float* arow = As + (size_t)wid * C_;
    float* brow = Bm + (size_t)wid * C_;
    float tot = 0.f;
#pragma unroll
    for (int q = 0; q < 3; ++q) {
        int c = lane + q * 64;
        float m  = mrow[c];
        float lp = lrow[c];
        float s2r = __expf(-2.f * lp);
        arow[c] = m * s2r;
        brow[c] = s2r;
        tot += (-HALF_LOG_2PI - lp) + (-0.5f * m * m * s2r);
    }
#pragma unroll
    for (int off = 32; off > 0; off >>= 1) tot += __shfl_xor(tot, off);
    if (lane == 0) nc14[wid] = tot;
}

// ---------------- GEMM: ll[b,t,s] = masked(nc14 + sum_c z*As + (-0.5 z^2)*Bm) ----------------
#define BM 64
#define BN 64
#define KB 16
__global__ __launch_bounds__(256)
void gemm_kernel(const float* __restrict__ z_p,
                 const float* __restrict__ As, const float* __restrict__ Bm,
                 const float* __restrict__ nc14,
                 const int* __restrict__ textlen, const int* __restrict__ mellen,
                 float* __restrict__ ll) {
    __shared__ float Zs[KB][BM + 4];
    __shared__ float Asb[KB][BN + 4];
    __shared__ float Bsb[KB][BN + 4];
    const int b  = blockIdx.z;
    const int t0 = blockIdx.y * BM;
    const int s0 = blockIdx.x * BN;
    const int tid = threadIdx.x;
    const int tx = tid & 15, ty = tid >> 4;
    const int i  = tid >> 2;             // 0..63 row within tile
    const int j4 = (tid & 3) * 4;        // 0,4,8,12 col within k-slab

    float acc[4][4];
#pragma unroll
    for (int a = 0; a < 4; ++a)
#pragma unroll
        for (int bq = 0; bq < 4; ++bq) acc[a][bq] = 0.f;

    const float* zb = z_p + ((size_t)b * T_ + t0 + i) * C_ + j4;
    const float* ab = As  + ((size_t)b * S_ + s0 + i) * C_ + j4;
    const float* bb = Bm  + ((size_t)b * S_ + s0 + i) * C_ + j4;

    for (int kt = 0; kt < C_ / KB; ++kt) {
        const int c0 = kt * KB;
        float4 zv = *(const float4*)(zb + c0);
        float4 av = *(const float4*)(ab + c0);
        float4 bv = *(const float4*)(bb + c0);
        __syncthreads();
        Zs[j4 + 0][i] = zv.x; Zs[j4 + 1][i] = zv.y; Zs[j4 + 2][i] = zv.z; Zs[j4 + 3][i] = zv.w;
        Asb[j4 + 0][i] = av.x; Asb[j4 + 1][i] = av.y; Asb[j4 + 2][i] = av.z; Asb[j4 + 3][i] = av.w;
        Bsb[j4 + 0][i] = bv.x; Bsb[j4 + 1][i] = bv.y; Bsb[j4 + 2][i] = bv.z; Bsb[j4 + 3][i] = bv.w;
        __syncthreads();
#pragma unroll
        for (int c = 0; c < KB; ++c) {
            float zr[4], wr[4], a4[4], b4[4];
#pragma unroll
            for (int r = 0; r < 4; ++r) {
                zr[r] = Zs[c][ty * 4 + r];
                a4[r] = Asb[c][tx * 4 + r];
                b4[r] = Bsb[c][tx * 4 + r];
            }
#pragma unroll
            for (int r = 0; r < 4; ++r) wr[r] = -0.5f * zr[r] * zr[r];
#pragma unroll
            for (int r = 0; r < 4; ++r)
#pragma unroll
                for (int q = 0; q < 4; ++q) {
                    acc[r][q] += zr[r] * a4[q];
                    acc[r][q] += wr[r] * b4[q];
                }
        }
    }

    const int ml = mellen[b], tl = textlen[b];
    float nc[4];
#pragma unroll
    for (int q = 0; q < 4; ++q) nc[q] = nc14[b * S_ + s0 + tx * 4 + q];
#pragma unroll
    for (int r = 0; r < 4; ++r) {
        const int t = t0 + ty * 4 + r;
        const bool tm = (t < ml);
        float* orow = ll + ((size_t)b * T_ + t) * S_ + s0 + tx * 4;
#pragma unroll
        for (int q = 0; q < 4; ++q) {
            const int s = s0 + tx * 4 + q;
            orow[q] = (tm && s < tl) ? (acc[r][q] + nc[q]) : NEGV;
        }
    }
}

// ---------------- MAS forward: register prefetch ring (float4), phase-split ----------------
__global__ __launch_bounds__(64)
void mas_forward(const float* __restrict__ ll, unsigned char* __restrict__ dir) {
    const int b = blockIdx.x;
    const int lane = threadIdx.x;
    const float* llb = ll + (size_t)b * T_ * S_ + lane * 8;
    unsigned char* db = dir + ((size_t)b * T_) * 64 + lane;
    const int sbase = lane * 8;

    // 8-row register prefetch ring: 2 float4 per row -> 16 outstanding loads max
    float4 pre[8][2];
#pragma unroll
    for (int r = 0; r < 8; ++r) {
        pre[r][0] = *(const float4*)(llb + (size_t)r * S_);
        pre[r][1] = *(const float4*)(llb + (size_t)r * S_ + 4);
    }

    float p[8];
#pragma unroll
    for (int j = 0; j < 8; ++j) p[j] = 0.f;
    // carry = previous lane's p[7] from the previous step (NEGV for lane 0)
    float carry = (lane == 0) ? NEGV : 0.f;

    auto step = [&](int t, int ph, bool masked) {
        float cur[8];
        cur[0] = pre[ph][0].x; cur[1] = pre[ph][0].y;
        cur[2] = pre[ph][0].z; cur[3] = pre[ph][0].w;
        cur[4] = pre[ph][1].x; cur[5] = pre[ph][1].y;
        cur[6] = pre[ph][1].z; cur[7] = pre[ph][1].w;
        const int tn = t + 8;
        if (tn < T_) {
            pre[ph][0] = *(const float4*)(llb + (size_t)tn * S_);
            pre[ph][1] = *(const float4*)(llb + (size_t)tn * S_ + 4);
        }
        // new p[7] first so the shfl for the next step issues early
        float v7 = fmaxf(p[7], p[6]) + cur[7];
        float nc7 = masked ? ((sbase + 7 <= t) ? v7 : NEGV) : v7;
        float newcarry = __shfl_up(nc7, 1);

        unsigned bits = (p[0] >= carry) ? 1u : 0u;
#pragma unroll
        for (int j = 1; j < 8; ++j)
            bits |= (p[j] >= p[j - 1] ? 1u : 0u) << j;

        float nv[8];
        nv[0] = fmaxf(p[0], carry) + cur[0];
#pragma unroll
        for (int j = 1; j < 7; ++j) nv[j] = fmaxf(p[j], p[j - 1]) + cur[j];
        nv[7] = v7;
        if (masked) {
#pragma unroll
            for (int j = 0; j < 8; ++j)
                p[j] = (sbase + j <= t) ? nv[j] : NEGV;
        } else {
#pragma unroll
            for (int j = 0; j < 8; ++j) p[j] = nv[j];
        }
        carry = (lane == 0) ? NEGV : newcarry;
        db[(size_t)t * 64] = (unsigned char)bits;
    };

    // phase 1: t in [0,512) — s<=t masking active
    for (int to = 0; to < S_ / 8; ++to) {
#pragma unroll
        for (int ph = 0; ph < 8; ++ph) step(to * 8 + ph, ph, true);
    }
    // phase 2: t in [512,2048) — all s<=t, no masking
    for (int to = S_ / 8; to < T_ / 8; ++to) {
#pragma unroll
        for (int ph = 0; ph < 8; ++ph) step(to * 8 + ph, ph, false);
    }
}

// ---------------- MAS backward: 8-step speculative groups, emits idx[b,t] ----------------
__global__ __launch_bounds__(64)
void mas_backward(const unsigned char* __restrict__ dir,
                  const int* __restrict__ textlen, const int* __restrict__ mellen,
                  int* __restrict__ idx_arr) {
    const int b = blockIdx.x;
    const int lane = threadIdx.x;
    const int tl = textlen[b], ml = mellen[b];
    for (int t = ml + lane; t < T_; t += 64) idx_arr[b * T_ + t] = -1;
    const unsigned char* db = dir + ((size_t)b * T_) * 64;
    int idx = tl - 1;
    int t_hi = ml - 1;
    while (t_hi >= 0) {
        const int lo = idx - 7;
        const int blo = (lo > 0 ? lo : 0) >> 3;
        const int bhi = idx >> 3;
        const int t = t_hi - lane;
        unsigned v = 0;
        if (lane < 8 && t >= 0) {
            unsigned b0 = db[(size_t)t * 64 + blo];
            unsigned b1 = db[(size_t)t * 64 + bhi];
            v = b0 | (b1 << 8);
        }
        unsigned vk[8];
#pragma unroll
        for (int k = 0; k < 8; ++k) vk[k] = __shfl((int)v, k);
        int emit = -1;
#pragma unroll
        for (int k = 0; k < 8; ++k) {
            const int tt = t_hi - k;
            if (tt < 0) break;
            if (lane == k) emit = idx;
            const int sb = idx >> 3;
            const unsigned byte = (sb == bhi) ? (vk[k] >> 8) : (vk[k] & 0xffu);
            const int stay = (byte >> (idx & 7)) & 1;
            idx -= (1 - stay);
            if (idx < 0) idx = 0;
        }
        const int tt = t_hi - lane;
        if (lane < 8 && tt >= 0) idx_arr[b * T_ + tt] = emit;
        t_hi -= 8;
    }
}

// ---------------- scatter the one-hots ----------------
__global__ __launch_bounds__(256)
void scatter_attn(const int* __restrict__ idx_arr, float* __restrict__ attn) {
    const int f = blockIdx.x * blockDim.x + threadIdx.x;  // b*T + t
    if (f >= B_ * T_) return;
    const int idx = idx_arr[f];
    if (idx >= 0) attn[(size_t)f * S_ + idx] = 1.0f;
}

// ---------------- per-frame kl ----------------
__global__ __launch_bounds__(256)
void kl_frames(const float* __restrict__ m_p, const float* __restrict__ logs_p,
               const float* __restrict__ z_p, const float* __restrict__ logs_q,
               const int* __restrict__ idx_arr, const int* __restrict__ mellen,
               float* __restrict__ frame_kl) {
    const int wid = (blockIdx.x * blockDim.x + threadIdx.x) >> 6;  // b*T + t
    const int lane = threadIdx.x & 63;
    if (wid >= B_ * T_) return;
    const int b = wid >> 11;       // T_ = 2048
    const int t = wid & (T_ - 1);
    const int ml = mellen[b];
    float total = 0.f;
    if (t < ml) {
        const int idx = idx_arr[wid];
        const float* mr = m_p    + ((size_t)b * S_ + idx) * C_;
        const float* lr = logs_p + ((size_t)b * S_ + idx) * C_;
        const float* zr = z_p    + (size_t)wid * C_;
        const float* qr = logs_q + (size_t)wid * C_;
#pragma unroll
        for (int q = 0; q < 3; ++q) {
            const int c = lane + q * 64;
            const float le = lr[c];
            const float d = zr[c] - mr[c];
            total += le - qr[c] - 0.5f + 0.5f * d * d * __expf(-2.f * le);
        }
    }
#pragma unroll
    for (int off = 32; off > 0; off >>= 1) total += __shfl_xor(total, off);
    if (lane == 0) frame_kl[wid] = total;
}

// ---------------- deterministic final reduce ----------------
__global__ __launch_bounds__(256)
void kl_reduce(const float* __restrict__ frame_kl, const int* __restrict__ mellen,
               float* __restrict__ out) {
    __shared__ float sm[256];
    const int tid = threadIdx.x;
    float s = 0.f;
    for (int k = tid; k < B_ * T_; k += 256) s += frame_kl[k];
    sm[tid] = s;
    __syncthreads();
    for (int off = 128; off > 0; off >>= 1) {
        if (tid < off) sm[tid] += sm[tid + off];
        __syncthreads();
    }
    if (tid == 0) {
        int sum_ml = 0;
        for (int bq = 0; bq < B_; ++bq) sum_ml += mellen[bq];
        out[0] = sm[0] / (float)sum_ml;
    }
}

extern "C" void kernel_launch(void* const* d_in, const int* in_sizes, int n_in,
                              void* d_out, int out_size, void* d_ws, size_t ws_size,
                              hipStream_t stream) {
    const float* m_p    = (const float*)d_in[0];
    const float* logs_p = (const float*)d_in[1];
    const float* z_p    = (const float*)d_in[2];
    const float* logs_q = (const float*)d_in[3];
    const int*   textlen = (const int*)d_in[4];
    const int*   mellen  = (const int*)d_in[5];

    float* out = (float*)d_out;
    float* attn = out + 1;                 // [B,T,S] region; also used as ll scratch
    float* ll = attn;

    char* ws = (char*)d_ws;
    const size_t OFF_AS   = 0;
    const size_t OFF_BM   = OFF_AS + (size_t)B_ * S_ * C_ * 4;   //  6291456
    const size_t OFF_NC   = OFF_BM + (size_t)B_ * S_ * C_ * 4;   // 12582912
    const size_t OFF_DIR  = OFF_NC + (size_t)B_ * S_ * 4;        // 12615680
    const size_t OFF_IDX  = OFF_DIR + (size_t)B_ * T_ * 64;      // 14712832
    const size_t OFF_FKL  = OFF_IDX + (size_t)B_ * T_ * 4;       // 14843904
    float* As   = (float*)(ws + OFF_AS);
    float* Bm   = (float*)(ws + OFF_BM);
    float* nc14 = (float*)(ws + OFF_NC);
    unsigned char* dir = (unsigned char*)(ws + OFF_DIR);
    int* idx_arr = (int*)(ws + OFF_IDX);
    float* frame_kl = (float*)(ws + OFF_FKL);

    // 1. prep
    prep_kernel<<<(B_ * S_) / 4, 256, 0, stream>>>(m_p, logs_p, As, Bm, nc14);
    // 2. score GEMM -> ll (in d_out attn region)
    gemm_kernel<<<dim3(S_ / BN, T_ / BM, B_), 256, 0, stream>>>(
        z_p, As, Bm, nc14, textlen, mellen, ll);
    // 3. MAS forward
    mas_forward<<<B_, 64, 0, stream>>>(ll, dir);
    // 4. MAS backward -> idx per frame
    mas_backward<<<B_, 64, 0, stream>>>(dir, textlen, mellen, idx_arr);
    // 5. zero attn then scatter ones
    hipMemsetAsync(attn, 0, (size_t)B_ * T_ * S_ * 4, stream);
    scatter_attn<<<(B_ * T_ + 255) / 256, 256, 0, stream>>>(idx_arr, attn);
    // 6. kl
    kl_frames<<<(B_ * T_) / 4, 256, 0, stream>>>(m_p, logs_p, z_p, logs_q,
                                                 idx_arr, mellen, frame_kl);
    kl_reduce<<<1, 256, 0, stream>>>(frame_kl, mellen, out);
}